// Round 1
// baseline (1205.516 us; speedup 1.0000x reference)
//
#include <hip/hip_runtime.h>
#include <math.h>

// Problem constants (B,Cin,Ce,Ci,Cout,H,W,K) = (16,32,32,32,32,128,128,3)
#define BB 16
#define C  32
#define H  128
#define W  128
#define TILE 16
#define THALO 18   // TILE + 2 halo

// d_ws layout (floats)
#define WS_WX    0        // [32][64][9] combined targets (o<32: ->e, o>=32: ->i), source x, raw
#define WS_WHE   18432    // source h_e: relu(W_e_e)/relu(W_e_i)
#define WS_WHI   36864    // source h_i: -relu(W_i_e)/-relu(W_i_i)  (sign folded)
#define WS_WOUT  55296    // [32][32][9] relu(W_e_out)
#define WS_BE    64512    // combined bias for cand_e: b_in_e + relu(b_e_e) - relu(b_i_e)
#define WS_BI    64544
#define WS_BOUT  64576    // relu(b_e_out)
#define WS_ITE   64608    // 1/max(tau_e,1)
#define WS_ITI   64640
// total 64672 floats = 258,688 bytes of d_ws

#define HE_OFF   ((size_t)BB*C*H*W)      // 8,388,608
#define HI_OFF   ((size_t)2*BB*C*H*W)

__device__ __forceinline__ float fast_tanh(float x) {
  // tanh(x) = sign(x) * (1 - 2/(exp(2|x|)+1)); safe as exp -> inf
  float ax = fabsf(x);
  float e  = __expf(2.f * ax);
  float t  = 1.f - 2.f / (e + 1.f);
  return copysignf(t, x);
}

// ---------------- Kernel 0: weight/bias preprocessing --------------------
__global__ void prep_kernel(const float* __restrict__ W_in_e, const float* __restrict__ b_in_e,
                            const float* __restrict__ W_in_i, const float* __restrict__ b_in_i,
                            const float* __restrict__ W_e_e,  const float* __restrict__ b_e_e,
                            const float* __restrict__ W_e_i,  const float* __restrict__ b_e_i,
                            const float* __restrict__ W_e_out,const float* __restrict__ b_e_out,
                            const float* __restrict__ W_i_e,  const float* __restrict__ b_i_e,
                            const float* __restrict__ W_i_i,  const float* __restrict__ b_i_i,
                            const float* __restrict__ tau_e,  const float* __restrict__ tau_i,
                            float* __restrict__ ws) {
  int i = blockIdx.x * 256 + threadIdx.x;
  if (i < 18432) {
    int cin = i / 576;
    int rem = i % 576;
    int o   = rem / 9;
    int k   = rem % 9;
    float wx, whe, whi;
    if (o < C) {
      int s = (o*C + cin)*9 + k;           // OIHW flat, target e
      wx  = W_in_e[s];
      whe = fmaxf(W_e_e[s], 0.f);
      whi = -fmaxf(W_i_e[s], 0.f);
    } else {
      int s = ((o-C)*C + cin)*9 + k;       // target i
      wx  = W_in_i[s];
      whe = fmaxf(W_e_i[s], 0.f);
      whi = -fmaxf(W_i_i[s], 0.f);
    }
    ws[WS_WX  + i] = wx;
    ws[WS_WHE + i] = whe;
    ws[WS_WHI + i] = whi;
  }
  if (i < 9216) {
    int cin = i / 288;
    int rem = i % 288;
    int o   = rem / 9;
    int k   = rem % 9;
    ws[WS_WOUT + i] = fmaxf(W_e_out[(o*C + cin)*9 + k], 0.f);
  }
  if (i < C) {
    ws[WS_BE   + i] = b_in_e[i] + fmaxf(b_e_e[i], 0.f) - fmaxf(b_i_e[i], 0.f);
    ws[WS_BI   + i] = b_in_i[i] + fmaxf(b_e_i[i], 0.f) - fmaxf(b_i_i[i], 0.f);
    ws[WS_BOUT + i] = fmaxf(b_e_out[i], 0.f);
    ws[WS_ITE  + i] = 1.f / fmaxf(tau_e[i], 1.f);
    ws[WS_ITI  + i] = 1.f / fmaxf(tau_i[i], 1.f);
  }
}

// ---------------- Kernel 1: fused cand_e/cand_i + state update -----------
// block = 256 threads, one 16x16 spatial tile of one batch image.
// Each thread owns one pixel, accumulates all 64 output channels (32 e + 32 i).
__global__ __launch_bounds__(256) void cell_kernel(
    const float* __restrict__ x, const float* __restrict__ h_e, const float* __restrict__ h_i,
    const float* __restrict__ ws, float* __restrict__ out) {
  __shared__ float tile[C][THALO][THALO];   // 41,472 B -> 3 blocks/CU

  const int b   = blockIdx.z;
  const int ty0 = blockIdx.y * TILE;
  const int tx0 = blockIdx.x * TILE;
  const int tid = threadIdx.x;
  const int ty  = tid >> 4;
  const int tx  = tid & 15;

  float acc[2*C];
  #pragma unroll
  for (int o = 0; o < C; ++o) {
    acc[o]     = ws[WS_BE + o];
    acc[C + o] = ws[WS_BI + o];
  }

  for (int s = 0; s < 3; ++s) {
    const float* src = (s == 0 ? x : (s == 1 ? h_e : h_i)) + (size_t)b*C*H*W;
    const float* wp  = ws + (s == 0 ? WS_WX : (s == 1 ? WS_WHE : WS_WHI));

    __syncthreads();
    for (int i = tid; i < C*THALO*THALO; i += 256) {
      int c   = i / (THALO*THALO);
      int rr  = i % (THALO*THALO);
      int r   = rr / THALO;
      int col = rr % THALO;
      int gr = ty0 - 1 + r;
      int gc = tx0 - 1 + col;
      float v = 0.f;
      if ((unsigned)gr < H && (unsigned)gc < W) v = src[(c*H + gr)*W + gc];
      tile[c][r][col] = v;
    }
    __syncthreads();

    for (int cin = 0; cin < C; ++cin) {
      float v[9];
      #pragma unroll
      for (int dy = 0; dy < 3; ++dy)
        #pragma unroll
        for (int dx = 0; dx < 3; ++dx)
          v[dy*3+dx] = tile[cin][ty+dy][tx+dx];

      const float* wc = wp + cin*(2*C*9);   // 576 contiguous, wave-uniform
      #pragma unroll
      for (int o = 0; o < 2*C; ++o) {
        float a = acc[o];
        #pragma unroll
        for (int k = 0; k < 9; ++k) a = fmaf(wc[o*9+k], v[k], a);
        acc[o] = a;
      }
    }
  }

  // epilogue: tanh + leaky integration, write new states
  const int gy = ty0 + ty;
  const int gx = tx0 + tx;
  #pragma unroll
  for (int o = 0; o < C; ++o) {
    size_t idx = ((size_t)(b*C + o)*H + gy)*W + gx;
    float ite = ws[WS_ITE + o];
    float hen = (1.f - ite) * h_e[idx] + ite * fast_tanh(acc[o]);
    out[HE_OFF + idx] = hen;
    float iti = ws[WS_ITI + o];
    float hin = (1.f - iti) * h_i[idx] + iti * fast_tanh(acc[C + o]);
    out[HI_OFF + idx] = hin;
  }
}

// ---------------- Kernel 2: output conv from h_e_new ----------------------
__global__ __launch_bounds__(256) void out_kernel(
    const float* __restrict__ ws, float* __restrict__ out) {
  __shared__ float tile[C][THALO][THALO];

  const int b   = blockIdx.z;
  const int ty0 = blockIdx.y * TILE;
  const int tx0 = blockIdx.x * TILE;
  const int tid = threadIdx.x;
  const int ty  = tid >> 4;
  const int tx  = tid & 15;

  const float* hen = out + HE_OFF + (size_t)b*C*H*W;

  float acc[C];
  #pragma unroll
  for (int o = 0; o < C; ++o) acc[o] = ws[WS_BOUT + o];

  for (int i = tid; i < C*THALO*THALO; i += 256) {
    int c   = i / (THALO*THALO);
    int rr  = i % (THALO*THALO);
    int r   = rr / THALO;
    int col = rr % THALO;
    int gr = ty0 - 1 + r;
    int gc = tx0 - 1 + col;
    float v = 0.f;
    if ((unsigned)gr < H && (unsigned)gc < W) v = hen[(c*H + gr)*W + gc];
    tile[c][r][col] = v;
  }
  __syncthreads();

  for (int cin = 0; cin < C; ++cin) {
    float v[9];
    #pragma unroll
    for (int dy = 0; dy < 3; ++dy)
      #pragma unroll
      for (int dx = 0; dx < 3; ++dx)
        v[dy*3+dx] = tile[cin][ty+dy][tx+dx];

    const float* wc = ws + WS_WOUT + cin*(C*9);
    #pragma unroll
    for (int o = 0; o < C; ++o) {
      float a = acc[o];
      #pragma unroll
      for (int k = 0; k < 9; ++k) a = fmaf(wc[o*9+k], v[k], a);
      acc[o] = a;
    }
  }

  const int gy = ty0 + ty;
  const int gx = tx0 + tx;
  #pragma unroll
  for (int o = 0; o < C; ++o) {
    size_t idx = ((size_t)(b*C + o)*H + gy)*W + gx;
    out[idx] = fast_tanh(acc[o]);
  }
}

// ---------------- launch --------------------------------------------------
extern "C" void kernel_launch(void* const* d_in, const int* in_sizes, int n_in,
                              void* d_out, int out_size, void* d_ws, size_t ws_size,
                              hipStream_t stream) {
  const float* x      = (const float*)d_in[0];
  const float* h_e    = (const float*)d_in[1];
  const float* h_i    = (const float*)d_in[2];
  const float* W_in_e = (const float*)d_in[3];
  const float* b_in_e = (const float*)d_in[4];
  const float* W_in_i = (const float*)d_in[5];
  const float* b_in_i = (const float*)d_in[6];
  const float* W_e_e  = (const float*)d_in[7];
  const float* b_e_e  = (const float*)d_in[8];
  const float* W_e_i  = (const float*)d_in[9];
  const float* b_e_i  = (const float*)d_in[10];
  const float* W_e_out= (const float*)d_in[11];
  const float* b_e_out= (const float*)d_in[12];
  const float* W_i_e  = (const float*)d_in[13];
  const float* b_i_e  = (const float*)d_in[14];
  const float* W_i_i  = (const float*)d_in[15];
  const float* b_i_i  = (const float*)d_in[16];
  const float* tau_e  = (const float*)d_in[17];
  const float* tau_i  = (const float*)d_in[18];

  float* ws  = (float*)d_ws;
  float* out = (float*)d_out;

  prep_kernel<<<72, 256, 0, stream>>>(W_in_e, b_in_e, W_in_i, b_in_i,
                                      W_e_e, b_e_e, W_e_i, b_e_i,
                                      W_e_out, b_e_out, W_i_e, b_i_e,
                                      W_i_i, b_i_i, tau_e, tau_i, ws);

  dim3 grid(W/TILE, H/TILE, BB);   // 8 x 8 x 16 = 1024 blocks
  cell_kernel<<<grid, 256, 0, stream>>>(x, h_e, h_i, ws, out);
  out_kernel<<<grid, 256, 0, stream>>>(ws, out);
}

// Round 2
// 770.729 us; speedup vs baseline: 1.5641x; 1.5641x over previous
//
#include <hip/hip_runtime.h>
#include <math.h>

// Problem constants (B,Cin,Ce,Ci,Cout,H,W,K) = (16,32,32,32,32,128,128,3)
#define BB 16
#define C  32
#define H  128
#define W  128
#define TY 8
#define TX 16
#define HY 10          // TY + 2 halo
#define HX 18          // TX + 2 halo
#define CPH 16         // channels staged per phase
#define NTHR 128

// d_ws layout (floats)
#define WS_WX    0        // [32][64][9] combined targets (o<32: ->e, o>=32: ->i), source x
#define WS_WHE   18432    // source h_e: relu(W_e_e)/relu(W_e_i)
#define WS_WHI   36864    // source h_i: -relu(W_i_e)/-relu(W_i_i)  (sign folded)
#define WS_WOUT  55296    // [32][32][9] relu(W_e_out)
#define WS_BE    64512    // b_in_e + relu(b_e_e) - relu(b_i_e)
#define WS_BI    64544
#define WS_BOUT  64576
#define WS_ITE   64608    // 1/max(tau_e,1)
#define WS_ITI   64640

#define HE_OFF   ((size_t)BB*C*H*W)
#define HI_OFF   ((size_t)2*BB*C*H*W)

__device__ __forceinline__ float fast_tanh(float x) {
  float ax = fabsf(x);
  float e  = __expf(2.f * ax);
  float t  = 1.f - 2.f / (e + 1.f);
  return copysignf(t, x);
}

// ---------------- Kernel 0: weight/bias preprocessing --------------------
__global__ void prep_kernel(const float* __restrict__ W_in_e, const float* __restrict__ b_in_e,
                            const float* __restrict__ W_in_i, const float* __restrict__ b_in_i,
                            const float* __restrict__ W_e_e,  const float* __restrict__ b_e_e,
                            const float* __restrict__ W_e_i,  const float* __restrict__ b_e_i,
                            const float* __restrict__ W_e_out,const float* __restrict__ b_e_out,
                            const float* __restrict__ W_i_e,  const float* __restrict__ b_i_e,
                            const float* __restrict__ W_i_i,  const float* __restrict__ b_i_i,
                            const float* __restrict__ tau_e,  const float* __restrict__ tau_i,
                            float* __restrict__ ws) {
  int i = blockIdx.x * 256 + threadIdx.x;
  if (i < 18432) {
    int cin = i / 576;
    int rem = i % 576;
    int o   = rem / 9;
    int k   = rem % 9;
    float wx, whe, whi;
    if (o < C) {
      int s = (o*C + cin)*9 + k;           // OIHW flat, target e
      wx  = W_in_e[s];
      whe = fmaxf(W_e_e[s], 0.f);
      whi = -fmaxf(W_i_e[s], 0.f);
    } else {
      int s = ((o-C)*C + cin)*9 + k;       // target i
      wx  = W_in_i[s];
      whe = fmaxf(W_e_i[s], 0.f);
      whi = -fmaxf(W_i_i[s], 0.f);
    }
    ws[WS_WX  + i] = wx;
    ws[WS_WHE + i] = whe;
    ws[WS_WHI + i] = whi;
  }
  if (i < 9216) {
    int cin = i / 288;
    int rem = i % 288;
    int o   = rem / 9;
    int k   = rem % 9;
    ws[WS_WOUT + i] = fmaxf(W_e_out[(o*C + cin)*9 + k], 0.f);
  }
  if (i < C) {
    ws[WS_BE   + i] = b_in_e[i] + fmaxf(b_e_e[i], 0.f) - fmaxf(b_i_e[i], 0.f);
    ws[WS_BI   + i] = b_in_i[i] + fmaxf(b_e_i[i], 0.f) - fmaxf(b_i_i[i], 0.f);
    ws[WS_BOUT + i] = fmaxf(b_e_out[i], 0.f);
    ws[WS_ITE  + i] = 1.f / fmaxf(tau_e[i], 1.f);
    ws[WS_ITI  + i] = 1.f / fmaxf(tau_i[i], 1.f);
  }
}

// ---------------- Kernel 1: fused cand_e/cand_i + state update -----------
// 128 threads, one 16x8 spatial tile; thread = 1 pixel, 64 accumulators.
// Sources staged 16 channels at a time (11.5 KB LDS) for high occupancy.
__global__ __launch_bounds__(NTHR) void cell_kernel(
    const float* __restrict__ x, const float* __restrict__ h_e, const float* __restrict__ h_i,
    const float* __restrict__ ws, float* __restrict__ out) {
  __shared__ float tile[CPH][HY][HX];   // 11,520 B

  const int b   = blockIdx.z;
  const int ty0 = blockIdx.y * TY;
  const int tx0 = blockIdx.x * TX;
  const int tid = threadIdx.x;
  const int ty  = tid >> 4;            // 0..7
  const int tx  = tid & 15;

  float acc[2*C];
  #pragma unroll
  for (int o = 0; o < C; ++o) {
    acc[o]     = ws[WS_BE + o];
    acc[C + o] = ws[WS_BI + o];
  }

  for (int s = 0; s < 3; ++s) {
    const float* src = (s == 0 ? x : (s == 1 ? h_e : h_i)) + (size_t)b*C*H*W;
    const float* wp  = ws + (s == 0 ? WS_WX : (s == 1 ? WS_WHE : WS_WHI));

    for (int half = 0; half < 2; ++half) {
      __syncthreads();
      for (int i = tid; i < CPH*HY*HX; i += NTHR) {
        int c   = i / (HY*HX);
        int rr  = i % (HY*HX);
        int r   = rr / HX;
        int col = rr % HX;
        int gr = ty0 - 1 + r;
        int gc = tx0 - 1 + col;
        float v = 0.f;
        if ((unsigned)gr < H && (unsigned)gc < W)
          v = src[((size_t)(half*CPH + c)*H + gr)*W + gc];
        tile[c][r][col] = v;
      }
      __syncthreads();

      const float* wh = wp + half*CPH*(2*C*9);
      for (int cin = 0; cin < CPH; ++cin) {
        float v[9];
        #pragma unroll
        for (int dy = 0; dy < 3; ++dy)
          #pragma unroll
          for (int dx = 0; dx < 3; ++dx)
            v[dy*3+dx] = tile[cin][ty+dy][tx+dx];

        const float* wc = wh + cin*(2*C*9);   // 576 contiguous, wave-uniform
        #pragma unroll
        for (int o = 0; o < 2*C; ++o) {
          float a = acc[o];
          #pragma unroll
          for (int k = 0; k < 9; ++k) a = fmaf(wc[o*9+k], v[k], a);
          acc[o] = a;
        }
      }
    }
  }

  // epilogue: tanh + leaky integration, write new states
  const int gy = ty0 + ty;
  const int gx = tx0 + tx;
  #pragma unroll
  for (int o = 0; o < C; ++o) {
    size_t idx = ((size_t)(b*C + o)*H + gy)*W + gx;
    float ite = ws[WS_ITE + o];
    float hen = (1.f - ite) * h_e[idx] + ite * fast_tanh(acc[o]);
    out[HE_OFF + idx] = hen;
    float iti = ws[WS_ITI + o];
    float hin = (1.f - iti) * h_i[idx] + iti * fast_tanh(acc[C + o]);
    out[HI_OFF + idx] = hin;
  }
}

// ---------------- Kernel 2: output conv from h_e_new ----------------------
__global__ __launch_bounds__(NTHR) void out_kernel(
    const float* __restrict__ ws, float* __restrict__ out) {
  __shared__ float tile[CPH][HY][HX];

  const int b   = blockIdx.z;
  const int ty0 = blockIdx.y * TY;
  const int tx0 = blockIdx.x * TX;
  const int tid = threadIdx.x;
  const int ty  = tid >> 4;
  const int tx  = tid & 15;

  const float* hen = out + HE_OFF + (size_t)b*C*H*W;

  float acc[C];
  #pragma unroll
  for (int o = 0; o < C; ++o) acc[o] = ws[WS_BOUT + o];

  for (int half = 0; half < 2; ++half) {
    __syncthreads();
    for (int i = tid; i < CPH*HY*HX; i += NTHR) {
      int c   = i / (HY*HX);
      int rr  = i % (HY*HX);
      int r   = rr / HX;
      int col = rr % HX;
      int gr = ty0 - 1 + r;
      int gc = tx0 - 1 + col;
      float v = 0.f;
      if ((unsigned)gr < H && (unsigned)gc < W)
        v = hen[((size_t)(half*CPH + c)*H + gr)*W + gc];
      tile[c][r][col] = v;
    }
    __syncthreads();

    const float* wh = ws + WS_WOUT + half*CPH*(C*9);
    for (int cin = 0; cin < CPH; ++cin) {
      float v[9];
      #pragma unroll
      for (int dy = 0; dy < 3; ++dy)
        #pragma unroll
        for (int dx = 0; dx < 3; ++dx)
          v[dy*3+dx] = tile[cin][ty+dy][tx+dx];

      const float* wc = wh + cin*(C*9);
      #pragma unroll
      for (int o = 0; o < C; ++o) {
        float a = acc[o];
        #pragma unroll
        for (int k = 0; k < 9; ++k) a = fmaf(wc[o*9+k], v[k], a);
        acc[o] = a;
      }
    }
  }

  const int gy = ty0 + ty;
  const int gx = tx0 + tx;
  #pragma unroll
  for (int o = 0; o < C; ++o) {
    size_t idx = ((size_t)(b*C + o)*H + gy)*W + gx;
    out[idx] = fast_tanh(acc[o]);
  }
}

// ---------------- launch --------------------------------------------------
extern "C" void kernel_launch(void* const* d_in, const int* in_sizes, int n_in,
                              void* d_out, int out_size, void* d_ws, size_t ws_size,
                              hipStream_t stream) {
  const float* x      = (const float*)d_in[0];
  const float* h_e    = (const float*)d_in[1];
  const float* h_i    = (const float*)d_in[2];
  const float* W_in_e = (const float*)d_in[3];
  const float* b_in_e = (const float*)d_in[4];
  const float* W_in_i = (const float*)d_in[5];
  const float* b_in_i = (const float*)d_in[6];
  const float* W_e_e  = (const float*)d_in[7];
  const float* b_e_e  = (const float*)d_in[8];
  const float* W_e_i  = (const float*)d_in[9];
  const float* b_e_i  = (const float*)d_in[10];
  const float* W_e_out= (const float*)d_in[11];
  const float* b_e_out= (const float*)d_in[12];
  const float* W_i_e  = (const float*)d_in[13];
  const float* b_i_e  = (const float*)d_in[14];
  const float* W_i_i  = (const float*)d_in[15];
  const float* b_i_i  = (const float*)d_in[16];
  const float* tau_e  = (const float*)d_in[17];
  const float* tau_i  = (const float*)d_in[18];

  float* ws  = (float*)d_ws;
  float* out = (float*)d_out;

  prep_kernel<<<72, 256, 0, stream>>>(W_in_e, b_in_e, W_in_i, b_in_i,
                                      W_e_e, b_e_e, W_e_i, b_e_i,
                                      W_e_out, b_e_out, W_i_e, b_i_e,
                                      W_i_i, b_i_i, tau_e, tau_i, ws);

  dim3 grid(W/TX, H/TY, BB);   // 8 x 16 x 16 = 2048 blocks
  cell_kernel<<<grid, NTHR, 0, stream>>>(x, h_e, h_i, ws, out);
  out_kernel<<<grid, NTHR, 0, stream>>>(ws, out);
}

// Round 7
// 378.206 us; speedup vs baseline: 3.1875x; 2.0379x over previous
//
#include <hip/hip_runtime.h>
#include <math.h>

// Problem constants (B,Cin,Ce,Ci,Cout,H,W,K) = (16,32,32,32,32,128,128,3)
#define BB 16
#define C  32
#define H  128
#define W  128

#define HE_OFF   ((size_t)BB*C*H*W)      // h_e_new at out + 8388608
#define HI_OFF   ((size_t)2*BB*C*H*W)    // h_i_new

// d_ws byte offsets (total ~130 KB)
#define WSB_WA    0         // wpackA fp16 [s3][tap9][mt4][lane64][j8] = 110592 B
#define WSB_WO    110592    // wpackO fp16 [tap9][mt2][lane64][j8]    = 18432 B
#define WSB_BIAS  129024    // f32[64]  combined cand bias (e||i)
#define WSB_ITAU  129280    // f32[64]  1/max(tau,1) (e||i)
#define WSB_BOUT  129536    // f32[32]  relu(b_e_out)

typedef _Float16 half8 __attribute__((ext_vector_type(8)));
typedef float    f32x4 __attribute__((ext_vector_type(4)));

__device__ __forceinline__ float fast_tanh(float x) {
  float ax = fabsf(x);
  float e  = __expf(2.f * ax);
  float t  = 1.f - 2.f / (e + 1.f);
  return copysignf(t, x);
}

// ---------------- Kernel 0: weight prepack into MFMA A-fragment order ----
// A-frag (16x16x32): lane l supplies A[row=l&15][k=(l>>4)*8+j], j=0..7.
// wpackA[s][tap][mt][lane][j] = Wcomb[s][ch=mt*16+(l&15)][cin=(l>>4)*8+j][tap]
__global__ void prep_kernel(const float* __restrict__ W_in_e, const float* __restrict__ b_in_e,
                            const float* __restrict__ W_in_i, const float* __restrict__ b_in_i,
                            const float* __restrict__ W_e_e,  const float* __restrict__ b_e_e,
                            const float* __restrict__ W_e_i,  const float* __restrict__ b_e_i,
                            const float* __restrict__ W_e_out,const float* __restrict__ b_e_out,
                            const float* __restrict__ W_i_e,  const float* __restrict__ b_i_e,
                            const float* __restrict__ W_i_i,  const float* __restrict__ b_i_i,
                            const float* __restrict__ tau_e,  const float* __restrict__ tau_i,
                            unsigned char* __restrict__ ws) {
  int t = blockIdx.x * 256 + threadIdx.x;
  _Float16* wa = (_Float16*)(ws + WSB_WA);
  _Float16* wo = (_Float16*)(ws + WSB_WO);
  float* bias64 = (float*)(ws + WSB_BIAS);
  float* itau64 = (float*)(ws + WSB_ITAU);
  float* bout   = (float*)(ws + WSB_BOUT);

  if (t < 55296) {
    int s = t / 18432, r1 = t % 18432;
    int tap = r1 / 2048, r2 = r1 % 2048;
    int mt = r2 / 512, r3 = r2 % 512;
    int lane = r3 >> 3, j = r3 & 7;
    int ch64 = mt*16 + (lane & 15);
    int cin  = (lane >> 4)*8 + j;
    int dy = tap / 3, dx = tap % 3;
    float v;
    if (ch64 < C) {
      int off = ((ch64*C + cin)*3 + dy)*3 + dx;
      v = (s==0) ? W_in_e[off] : (s==1) ? fmaxf(W_e_e[off],0.f) : -fmaxf(W_i_e[off],0.f);
    } else {
      int off = (((ch64-C)*C + cin)*3 + dy)*3 + dx;
      v = (s==0) ? W_in_i[off] : (s==1) ? fmaxf(W_e_i[off],0.f) : -fmaxf(W_i_i[off],0.f);
    }
    wa[t] = (_Float16)v;
  }
  if (t < 9216) {
    int tap = t / 1024, r2 = t % 1024;
    int mt = r2 / 512, r3 = r2 % 512;
    int lane = r3 >> 3, j = r3 & 7;
    int ch  = mt*16 + (lane & 15);
    int cin = (lane >> 4)*8 + j;
    int dy = tap / 3, dx = tap % 3;
    wo[t] = (_Float16)fmaxf(W_e_out[((ch*C + cin)*3 + dy)*3 + dx], 0.f);
  }
  if (t < 64) {
    if (t < 32) {
      bias64[t] = b_in_e[t] + fmaxf(b_e_e[t],0.f) - fmaxf(b_i_e[t],0.f);
      itau64[t] = 1.f / fmaxf(tau_e[t], 1.f);
      bout[t]   = fmaxf(b_e_out[t], 0.f);
    } else {
      bias64[t] = b_in_i[t-32] + fmaxf(b_e_i[t-32],0.f) - fmaxf(b_i_i[t-32],0.f);
      itau64[t] = 1.f / fmaxf(tau_i[t-32], 1.f);
    }
  }
}

// ---------------- Kernel 1: fused cand_e/cand_i MFMA + state update ------
// Block = 256 thr (4 waves), 16x16 pixel tile of one image.
// Wave w owns all 64 out-ch x 64 pixels (rows y = w*4..w*4+3 of the tile).
// Input staged fp32->fp16 channel-last in LDS with 16B-chunk XOR swizzle.
__global__ __launch_bounds__(256) void cell_kernel(
    const float* __restrict__ x, const float* __restrict__ h_e, const float* __restrict__ h_i,
    const unsigned char* __restrict__ ws, float* __restrict__ out) {
  __shared__ f32x4 smem[3600];                  // 57,600 B -> 2 blocks/CU
  _Float16* tile = (_Float16*)smem;             // [18 rows][18 cols][32 ch] = 20,736 B
  f32x4*    wlds = smem + 1296;                 // weights for current source, 36,864 B

  const int b   = blockIdx.z;
  const int ty0 = blockIdx.y * 16, tx0 = blockIdx.x * 16;
  const int tid = threadIdx.x;
  const int wid = tid >> 6, l = tid & 63;
  const int q   = l >> 4, xl = l & 15;

  const float* bias64 = (const float*)(ws + WSB_BIAS);
  const float* itau64 = (const float*)(ws + WSB_ITAU);

  f32x4 acc[4][4];
  #pragma unroll
  for (int mt = 0; mt < 4; ++mt) {
    f32x4 bv = *(const f32x4*)(bias64 + mt*16 + q*4);
    #pragma unroll
    for (int nt = 0; nt < 4; ++nt) acc[mt][nt] = bv;
  }

  for (int s = 0; s < 3; ++s) {
    const float* src = (s==0 ? x : (s==1 ? h_e : h_i)) + (size_t)b*C*H*W;
    __syncthreads();                            // previous source's compute done
    // stage input tile: fp32 NCHW (coalesced) -> fp16 channel-last, swizzled
    for (int i = tid; i < 10368; i += 256) {    // 32ch * 18 * 18
      int c = i / 324, rem = i % 324;
      int yy = rem / 18, xx = rem % 18;
      int gr = ty0 - 1 + yy, gc = tx0 - 1 + xx;
      float v = ((unsigned)gr < H && (unsigned)gc < W) ? src[(c*H + gr)*W + gc] : 0.f;
      int baddr = yy*1152 + xx*64 + (((c>>3) ^ ((xx>>1)&3)) << 4) + ((c&7) << 1);
      tile[baddr >> 1] = (_Float16)v;
    }
    // stage this source's prepacked weights (linear copy)
    const f32x4* wsrc = (const f32x4*)(ws + WSB_WA) + s*2304;
    #pragma unroll
    for (int k2 = 0; k2 < 9; ++k2) wlds[k2*256 + tid] = wsrc[k2*256 + tid];
    __syncthreads();

    #pragma unroll
    for (int dy = 0; dy < 3; ++dy) {
      #pragma unroll
      for (int dx = 0; dx < 3; ++dx) {
        const int tap  = dy*3 + dx;
        const int xcol = xl + dx;
        const int swz  = (q ^ ((xcol>>1)&3)) << 4;
        half8 bf[4];
        #pragma unroll
        for (int nt = 0; nt < 4; ++nt) {
          int yrow = wid*4 + nt + dy;
          bf[nt] = *(const half8*)((const char*)tile + yrow*1152 + xcol*64 + swz);
        }
        #pragma unroll
        for (int mt = 0; mt < 4; ++mt) {
          half8 af = *(const half8*)((const char*)wlds + ((tap*4 + mt)*64 + l)*16);
          #pragma unroll
          for (int nt = 0; nt < 4; ++nt)
            acc[mt][nt] = __builtin_amdgcn_mfma_f32_16x16x32_f16(af, bf[nt], acc[mt][nt], 0, 0, 0);
        }
      }
    }
  }

  // epilogue: C/D layout col=l&15 (pixel), row=(l>>4)*4+r (channel)
  #pragma unroll
  for (int mt = 0; mt < 4; ++mt) {
    f32x4 tv = *(const f32x4*)(itau64 + mt*16 + q*4);
    const float* hsrc = (mt < 2) ? h_e : h_i;
    float*       dst  = out + ((mt < 2) ? HE_OFF : HI_OFF);
    #pragma unroll
    for (int nt = 0; nt < 4; ++nt) {
      int pix = wid*64 + nt*16 + xl;
      int gy = ty0 + (pix >> 4), gx = tx0 + (pix & 15);
      #pragma unroll
      for (int r = 0; r < 4; ++r) {
        int ch = (mt*16 + q*4 + r) & 31;
        size_t idx = (((size_t)b*C + ch)*H + gy)*W + gx;
        float it = tv[r];
        dst[idx] = (1.f - it)*hsrc[idx] + it*fast_tanh(acc[mt][nt][r]);
      }
    }
  }
}

// ---------------- Kernel 2: output conv from h_e_new (MFMA) ---------------
__global__ __launch_bounds__(256) void out_kernel(
    const unsigned char* __restrict__ ws, float* __restrict__ out) {
  __shared__ f32x4 smem[2448];                  // 39,168 B -> 4 blocks/CU
  _Float16* tile = (_Float16*)smem;             // 20,736 B
  f32x4*    wlds = smem + 1296;                 // 18,432 B

  const int b   = blockIdx.z;
  const int ty0 = blockIdx.y * 16, tx0 = blockIdx.x * 16;
  const int tid = threadIdx.x;
  const int wid = tid >> 6, l = tid & 63;
  const int q   = l >> 4, xl = l & 15;

  const float* bout = (const float*)(ws + WSB_BOUT);
  const float* src  = out + HE_OFF + (size_t)b*C*H*W;

  f32x4 acc[2][4];
  #pragma unroll
  for (int mt = 0; mt < 2; ++mt) {
    f32x4 bv = *(const f32x4*)(bout + mt*16 + q*4);
    #pragma unroll
    for (int nt = 0; nt < 4; ++nt) acc[mt][nt] = bv;
  }

  for (int i = tid; i < 10368; i += 256) {
    int c = i / 324, rem = i % 324;
    int yy = rem / 18, xx = rem % 18;
    int gr = ty0 - 1 + yy, gc = tx0 - 1 + xx;
    float v = ((unsigned)gr < H && (unsigned)gc < W) ? src[(c*H + gr)*W + gc] : 0.f;
    int baddr = yy*1152 + xx*64 + (((c>>3) ^ ((xx>>1)&3)) << 4) + ((c&7) << 1);
    tile[baddr >> 1] = (_Float16)v;
  }
  const f32x4* wsrc = (const f32x4*)(ws + WSB_WO);
  #pragma unroll
  for (int k2 = 0; k2 < 5; ++k2) {
    int off = k2*256 + tid;
    if (off < 1152) wlds[off] = wsrc[off];
  }
  __syncthreads();

  #pragma unroll
  for (int dy = 0; dy < 3; ++dy) {
    #pragma unroll
    for (int dx = 0; dx < 3; ++dx) {
      const int tap  = dy*3 + dx;
      const int xcol = xl + dx;
      const int swz  = (q ^ ((xcol>>1)&3)) << 4;
      half8 bf[4];
      #pragma unroll
      for (int nt = 0; nt < 4; ++nt) {
        int yrow = wid*4 + nt + dy;
        bf[nt] = *(const half8*)((const char*)tile + yrow*1152 + xcol*64 + swz);
      }
      #pragma unroll
      for (int mt = 0; mt < 2; ++mt) {
        half8 af = *(const half8*)((const char*)wlds + ((tap*2 + mt)*64 + l)*16);
        #pragma unroll
        for (int nt = 0; nt < 4; ++nt)
          acc[mt][nt] = __builtin_amdgcn_mfma_f32_16x16x32_f16(af, bf[nt], acc[mt][nt], 0, 0, 0);
      }
    }
  }

  #pragma unroll
  for (int mt = 0; mt < 2; ++mt) {
    #pragma unroll
    for (int nt = 0; nt < 4; ++nt) {
      int pix = wid*64 + nt*16 + xl;
      int gy = ty0 + (pix >> 4), gx = tx0 + (pix & 15);
      #pragma unroll
      for (int r = 0; r < 4; ++r) {
        int ch = mt*16 + q*4 + r;
        out[(((size_t)b*C + ch)*H + gy)*W + gx] = fast_tanh(acc[mt][nt][r]);
      }
    }
  }
}

// ---------------- launch --------------------------------------------------
extern "C" void kernel_launch(void* const* d_in, const int* in_sizes, int n_in,
                              void* d_out, int out_size, void* d_ws, size_t ws_size,
                              hipStream_t stream) {
  const float* x      = (const float*)d_in[0];
  const float* h_e    = (const float*)d_in[1];
  const float* h_i    = (const float*)d_in[2];
  const float* W_in_e = (const float*)d_in[3];
  const float* b_in_e = (const float*)d_in[4];
  const float* W_in_i = (const float*)d_in[5];
  const float* b_in_i = (const float*)d_in[6];
  const float* W_e_e  = (const float*)d_in[7];
  const float* b_e_e  = (const float*)d_in[8];
  const float* W_e_i  = (const float*)d_in[9];
  const float* b_e_i  = (const float*)d_in[10];
  const float* W_e_out= (const float*)d_in[11];
  const float* b_e_out= (const float*)d_in[12];
  const float* W_i_e  = (const float*)d_in[13];
  const float* b_i_e  = (const float*)d_in[14];
  const float* W_i_i  = (const float*)d_in[15];
  const float* b_i_i  = (const float*)d_in[16];
  const float* tau_e  = (const float*)d_in[17];
  const float* tau_i  = (const float*)d_in[18];

  unsigned char* ws = (unsigned char*)d_ws;
  float* out = (float*)d_out;

  prep_kernel<<<216, 256, 0, stream>>>(W_in_e, b_in_e, W_in_i, b_in_i,
                                       W_e_e, b_e_e, W_e_i, b_e_i,
                                       W_e_out, b_e_out, W_i_e, b_i_e,
                                       W_i_i, b_i_i, tau_e, tau_i, ws);

  dim3 grid(W/16, H/16, BB);   // 8 x 8 x 16 = 1024 blocks
  cell_kernel<<<grid, 256, 0, stream>>>(x, h_e, h_i, ws, out);
  out_kernel<<<grid, 256, 0, stream>>>(ws, out);
}

// Round 8
// 314.440 us; speedup vs baseline: 3.8339x; 1.2028x over previous
//
#include <hip/hip_runtime.h>
#include <math.h>

// Problem constants (B,Cin,Ce,Ci,Cout,H,W,K) = (16,32,32,32,32,128,128,3)
#define BB 16
#define C  32
#define H  128
#define W  128

#define HE_OFF   ((size_t)BB*C*H*W)      // h_e_new at out + 8388608
#define HI_OFF   ((size_t)2*BB*C*H*W)    // h_i_new

// d_ws byte offsets. Weight block first (~130 KB), then fp16 NHWC tensors.
#define WSB_WA    0         // wpackA fp16 [s3][tap9][mt4][lane64][j8] = 110592 B
#define WSB_WO    110592    // wpackO fp16 [tap9][mt2][lane64][j8]    = 18432 B
#define WSB_BIAS  129024    // f32[64]  combined cand bias (e||i)
#define WSB_ITAU  129280    // f32[64]  1/max(tau,1) (e||i)
#define WSB_BOUT  129536    // f32[32]  relu(b_e_out)
#define WSB_F16   131072    // 4 fp16 NHWC tensors: x, h_e, h_i, h_e_new
#define TBYTES    16777216  // bytes per fp16 NHWC tensor (16*128*128*32*2)
#define IMGB      1048576   // bytes per image (128*128*32*2)
#define WS_NEED   (WSB_F16 + 4*(size_t)TBYTES)   // 67,239,936 B

typedef _Float16 half8 __attribute__((ext_vector_type(8)));
typedef _Float16 half4 __attribute__((ext_vector_type(4)));
typedef float    f32x4 __attribute__((ext_vector_type(4)));

__device__ __forceinline__ float fast_tanh(float x) {
  float ax = fabsf(x);
  float e  = __expf(2.f * ax);
  float t  = 1.f - 2.f / (e + 1.f);
  return copysignf(t, x);
}

// ---------------- Kernel 0: weight/bias prepack (unchanged, verified) ----
__global__ void prep_kernel(const float* __restrict__ W_in_e, const float* __restrict__ b_in_e,
                            const float* __restrict__ W_in_i, const float* __restrict__ b_in_i,
                            const float* __restrict__ W_e_e,  const float* __restrict__ b_e_e,
                            const float* __restrict__ W_e_i,  const float* __restrict__ b_e_i,
                            const float* __restrict__ W_e_out,const float* __restrict__ b_e_out,
                            const float* __restrict__ W_i_e,  const float* __restrict__ b_i_e,
                            const float* __restrict__ W_i_i,  const float* __restrict__ b_i_i,
                            const float* __restrict__ tau_e,  const float* __restrict__ tau_i,
                            unsigned char* __restrict__ ws) {
  int t = blockIdx.x * 256 + threadIdx.x;
  _Float16* wa = (_Float16*)(ws + WSB_WA);
  _Float16* wo = (_Float16*)(ws + WSB_WO);
  float* bias64 = (float*)(ws + WSB_BIAS);
  float* itau64 = (float*)(ws + WSB_ITAU);
  float* bout   = (float*)(ws + WSB_BOUT);

  if (t < 55296) {
    int s = t / 18432, r1 = t % 18432;
    int tap = r1 / 2048, r2 = r1 % 2048;
    int mt = r2 / 512, r3 = r2 % 512;
    int lane = r3 >> 3, j = r3 & 7;
    int ch64 = mt*16 + (lane & 15);
    int cin  = (lane >> 4)*8 + j;
    int dy = tap / 3, dx = tap % 3;
    float v;
    if (ch64 < C) {
      int off = ((ch64*C + cin)*3 + dy)*3 + dx;
      v = (s==0) ? W_in_e[off] : (s==1) ? fmaxf(W_e_e[off],0.f) : -fmaxf(W_i_e[off],0.f);
    } else {
      int off = (((ch64-C)*C + cin)*3 + dy)*3 + dx;
      v = (s==0) ? W_in_i[off] : (s==1) ? fmaxf(W_e_i[off],0.f) : -fmaxf(W_i_i[off],0.f);
    }
    wa[t] = (_Float16)v;
  }
  if (t < 9216) {
    int tap = t / 1024, r2 = t % 1024;
    int mt = r2 / 512, r3 = r2 % 512;
    int lane = r3 >> 3, j = r3 & 7;
    int ch  = mt*16 + (lane & 15);
    int cin = (lane >> 4)*8 + j;
    int dy = tap / 3, dx = tap % 3;
    wo[t] = (_Float16)fmaxf(W_e_out[((ch*C + cin)*3 + dy)*3 + dx], 0.f);
  }
  if (t < 64) {
    if (t < 32) {
      bias64[t] = b_in_e[t] + fmaxf(b_e_e[t],0.f) - fmaxf(b_i_e[t],0.f);
      itau64[t] = 1.f / fmaxf(tau_e[t], 1.f);
      bout[t]   = fmaxf(b_e_out[t], 0.f);
    } else {
      bias64[t] = b_in_i[t-32] + fmaxf(b_e_i[t-32],0.f) - fmaxf(b_i_i[t-32],0.f);
      itau64[t] = 1.f / fmaxf(tau_i[t-32], 1.f);
    }
  }
}

// ---------------- Kernel 0b: fp32 NCHW -> fp16 NHWC convert ---------------
// One block per (b,y): 128 lanes = x. Per channel the W-row read is
// coalesced; each lane packs 32 ch and writes 4x16B.
__global__ __launch_bounds__(128) void convert_kernel(
    const float* __restrict__ x, const float* __restrict__ he,
    const float* __restrict__ hi, unsigned char* __restrict__ ws) {
  const int bid = blockIdx.x;
  const int b = bid >> 7, y = bid & 127;
  const int lane = threadIdx.x;
  const float* srcs[3] = {x, he, hi};
  #pragma unroll
  for (int t = 0; t < 3; ++t) {
    const float* src = srcs[t] + (size_t)b*C*H*W + (size_t)y*W + lane;
    _Float16* dst = (_Float16*)(ws + WSB_F16 + (size_t)t*TBYTES)
                    + (size_t)b*(C*H*W) + ((size_t)y*W + lane)*C;
    half8 o[4];
    #pragma unroll
    for (int c = 0; c < 32; ++c)
      o[c>>3][c&7] = (_Float16)src[(size_t)c*H*W];
    #pragma unroll
    for (int k = 0; k < 4; ++k) *((half8*)dst + k) = o[k];
  }
}

// ---------------- Kernel 1: fused cand_e/cand_i MFMA + state update ------
// 256 thr (4 waves), 16x16 pixel tile. LDS = input tile only (20.7 KB ->
// 4+ blocks/CU resident). Weights read per-tap from global (L2-resident).
// Staging: 16B vector loads from fp16 NHWC, swizzled ds_write.
__global__ __launch_bounds__(256, 4) void cell_kernel(
    const unsigned char* __restrict__ ws, float* __restrict__ out) {
  __shared__ _Float16 tile[10368];              // [18 rows][18 cols][32 ch]

  const int b   = blockIdx.z;
  const int ty0 = blockIdx.y * 16, tx0 = blockIdx.x * 16;
  const int tid = threadIdx.x;
  const int wid = tid >> 6, l = tid & 63;
  const int q   = l >> 4, xl = l & 15;

  const float* bias64 = (const float*)(ws + WSB_BIAS);
  const float* itau64 = (const float*)(ws + WSB_ITAU);

  f32x4 acc[4][4];
  #pragma unroll
  for (int mt = 0; mt < 4; ++mt) {
    f32x4 bv = *(const f32x4*)(bias64 + mt*16 + q*4);
    #pragma unroll
    for (int nt = 0; nt < 4; ++nt) acc[mt][nt] = bv;
  }

  for (int s = 0; s < 3; ++s) {
    const unsigned char* src16 = ws + WSB_F16 + (size_t)s*TBYTES + (size_t)b*IMGB;
    __syncthreads();                            // previous source compute done
    for (int i = tid; i < 1296; i += 256) {     // 18*18*4 16B chunks
      int yy = i / 72, r = i % 72;
      int xx = r >> 2, k = r & 3;
      int gr = ty0 - 1 + yy, gc = tx0 - 1 + xx;
      half8 v;
      #pragma unroll
      for (int j = 0; j < 8; ++j) v[j] = (_Float16)0.f;
      if ((unsigned)gr < H && (unsigned)gc < W)
        v = *(const half8*)(src16 + (gr*W + gc)*64 + k*16);
      *(half8*)((char*)tile + yy*1152 + xx*64 + ((k ^ ((xx>>1)&3)) << 4)) = v;
    }
    __syncthreads();

    const unsigned char* wsrc = ws + WSB_WA + s*36864;
    #pragma unroll
    for (int dy = 0; dy < 3; ++dy) {
      #pragma unroll
      for (int dx = 0; dx < 3; ++dx) {
        const int tap  = dy*3 + dx;
        const int xcol = xl + dx;
        const int swz  = (q ^ ((xcol>>1)&3)) << 4;
        half8 bf[4];
        #pragma unroll
        for (int nt = 0; nt < 4; ++nt) {
          int yrow = wid*4 + nt + dy;
          bf[nt] = *(const half8*)((const char*)tile + yrow*1152 + xcol*64 + swz);
        }
        #pragma unroll
        for (int mt = 0; mt < 4; ++mt) {
          half8 af = *(const half8*)(wsrc + ((tap*4 + mt)*64 + l)*16);
          #pragma unroll
          for (int nt = 0; nt < 4; ++nt)
            acc[mt][nt] = __builtin_amdgcn_mfma_f32_16x16x32_f16(af, bf[nt], acc[mt][nt], 0, 0, 0);
        }
      }
    }
  }

  // epilogue: C/D col=l&15 (pixel), row=(l>>4)*4+r (channel)
  #pragma unroll
  for (int mt = 0; mt < 4; ++mt) {
    f32x4 tv = *(const f32x4*)(itau64 + mt*16 + q*4);
    const unsigned char* h16 = ws + WSB_F16 + (size_t)((mt < 2) ? 1 : 2)*TBYTES + (size_t)b*IMGB;
    unsigned char*     hen16 = (unsigned char*)ws + WSB_F16 + (size_t)3*TBYTES + (size_t)b*IMGB;
    float*             dst32 = out + ((mt < 2) ? HE_OFF : HI_OFF);
    const int chbase = (mt & 1)*16 + q*4;
    #pragma unroll
    for (int nt = 0; nt < 4; ++nt) {
      int pix = wid*64 + nt*16 + xl;
      int gy = ty0 + (pix >> 4), gx = tx0 + (pix & 15);
      int pixb = (gy*W + gx)*64;
      half4 hv = *(const half4*)(h16 + pixb + chbase*2);
      half4 h16out;
      #pragma unroll
      for (int r = 0; r < 4; ++r) {
        int ch = chbase + r;
        float it = tv[r];
        float res = (1.f - it)*(float)hv[r] + it*fast_tanh(acc[mt][nt][r]);
        dst32[(((size_t)b*C + ch)*H + gy)*W + gx] = res;
        h16out[r] = (_Float16)res;
      }
      if (mt < 2) *(half4*)(hen16 + pixb + chbase*2) = h16out;
    }
  }
}

// ---------------- Kernel 2: output conv from h_e_new (fp16 NHWC) ---------
__global__ __launch_bounds__(256, 4) void out_kernel(
    const unsigned char* __restrict__ ws, float* __restrict__ out) {
  __shared__ _Float16 tile[10368];

  const int b   = blockIdx.z;
  const int ty0 = blockIdx.y * 16, tx0 = blockIdx.x * 16;
  const int tid = threadIdx.x;
  const int wid = tid >> 6, l = tid & 63;
  const int q   = l >> 4, xl = l & 15;

  const float* bout = (const float*)(ws + WSB_BOUT);
  const unsigned char* src16 = ws + WSB_F16 + (size_t)3*TBYTES + (size_t)b*IMGB;

  f32x4 acc[2][4];
  #pragma unroll
  for (int mt = 0; mt < 2; ++mt) {
    f32x4 bv = *(const f32x4*)(bout + mt*16 + q*4);
    #pragma unroll
    for (int nt = 0; nt < 4; ++nt) acc[mt][nt] = bv;
  }

  for (int i = tid; i < 1296; i += 256) {
    int yy = i / 72, r = i % 72;
    int xx = r >> 2, k = r & 3;
    int gr = ty0 - 1 + yy, gc = tx0 - 1 + xx;
    half8 v;
    #pragma unroll
    for (int j = 0; j < 8; ++j) v[j] = (_Float16)0.f;
    if ((unsigned)gr < H && (unsigned)gc < W)
      v = *(const half8*)(src16 + (gr*W + gc)*64 + k*16);
    *(half8*)((char*)tile + yy*1152 + xx*64 + ((k ^ ((xx>>1)&3)) << 4)) = v;
  }
  __syncthreads();

  const unsigned char* wsrc = ws + WSB_WO;
  #pragma unroll
  for (int dy = 0; dy < 3; ++dy) {
    #pragma unroll
    for (int dx = 0; dx < 3; ++dx) {
      const int tap  = dy*3 + dx;
      const int xcol = xl + dx;
      const int swz  = (q ^ ((xcol>>1)&3)) << 4;
      half8 bf[4];
      #pragma unroll
      for (int nt = 0; nt < 4; ++nt) {
        int yrow = wid*4 + nt + dy;
        bf[nt] = *(const half8*)((const char*)tile + yrow*1152 + xcol*64 + swz);
      }
      #pragma unroll
      for (int mt = 0; mt < 2; ++mt) {
        half8 af = *(const half8*)(wsrc + ((tap*2 + mt)*64 + l)*16);
        #pragma unroll
        for (int nt = 0; nt < 4; ++nt)
          acc[mt][nt] = __builtin_amdgcn_mfma_f32_16x16x32_f16(af, bf[nt], acc[mt][nt], 0, 0, 0);
      }
    }
  }

  #pragma unroll
  for (int mt = 0; mt < 2; ++mt) {
    #pragma unroll
    for (int nt = 0; nt < 4; ++nt) {
      int pix = wid*64 + nt*16 + xl;
      int gy = ty0 + (pix >> 4), gx = tx0 + (pix & 15);
      #pragma unroll
      for (int r = 0; r < 4; ++r) {
        int ch = mt*16 + q*4 + r;
        out[(((size_t)b*C + ch)*H + gy)*W + gx] = fast_tanh(acc[mt][nt][r]);
      }
    }
  }
}

// ============= Fallback path (R2, HW-verified) for small ws ===============
__global__ __launch_bounds__(256) void cell_kernel_fb(
    const float* __restrict__ x, const float* __restrict__ h_e, const float* __restrict__ h_i,
    const unsigned char* __restrict__ ws, float* __restrict__ out) {
  __shared__ f32x4 smem[3600];
  _Float16* tile = (_Float16*)smem;
  f32x4*    wlds = smem + 1296;

  const int b   = blockIdx.z;
  const int ty0 = blockIdx.y * 16, tx0 = blockIdx.x * 16;
  const int tid = threadIdx.x;
  const int wid = tid >> 6, l = tid & 63;
  const int q   = l >> 4, xl = l & 15;

  const float* bias64 = (const float*)(ws + WSB_BIAS);
  const float* itau64 = (const float*)(ws + WSB_ITAU);

  f32x4 acc[4][4];
  #pragma unroll
  for (int mt = 0; mt < 4; ++mt) {
    f32x4 bv = *(const f32x4*)(bias64 + mt*16 + q*4);
    #pragma unroll
    for (int nt = 0; nt < 4; ++nt) acc[mt][nt] = bv;
  }

  for (int s = 0; s < 3; ++s) {
    const float* src = (s==0 ? x : (s==1 ? h_e : h_i)) + (size_t)b*C*H*W;
    __syncthreads();
    for (int i = tid; i < 10368; i += 256) {
      int c = i / 324, rem = i % 324;
      int yy = rem / 18, xx = rem % 18;
      int gr = ty0 - 1 + yy, gc = tx0 - 1 + xx;
      float v = ((unsigned)gr < H && (unsigned)gc < W) ? src[(c*H + gr)*W + gc] : 0.f;
      int baddr = yy*1152 + xx*64 + (((c>>3) ^ ((xx>>1)&3)) << 4) + ((c&7) << 1);
      tile[baddr >> 1] = (_Float16)v;
    }
    const f32x4* wsrc = (const f32x4*)(ws + WSB_WA) + s*2304;
    #pragma unroll
    for (int k2 = 0; k2 < 9; ++k2) wlds[k2*256 + tid] = wsrc[k2*256 + tid];
    __syncthreads();

    #pragma unroll
    for (int dy = 0; dy < 3; ++dy) {
      #pragma unroll
      for (int dx = 0; dx < 3; ++dx) {
        const int tap  = dy*3 + dx;
        const int xcol = xl + dx;
        const int swz  = (q ^ ((xcol>>1)&3)) << 4;
        half8 bf[4];
        #pragma unroll
        for (int nt = 0; nt < 4; ++nt) {
          int yrow = wid*4 + nt + dy;
          bf[nt] = *(const half8*)((const char*)tile + yrow*1152 + xcol*64 + swz);
        }
        #pragma unroll
        for (int mt = 0; mt < 4; ++mt) {
          half8 af = *(const half8*)((const char*)wlds + ((tap*4 + mt)*64 + l)*16);
          #pragma unroll
          for (int nt = 0; nt < 4; ++nt)
            acc[mt][nt] = __builtin_amdgcn_mfma_f32_16x16x32_f16(af, bf[nt], acc[mt][nt], 0, 0, 0);
        }
      }
    }
  }

  #pragma unroll
  for (int mt = 0; mt < 4; ++mt) {
    f32x4 tv = *(const f32x4*)(itau64 + mt*16 + q*4);
    const float* hsrc = (mt < 2) ? h_e : h_i;
    float*       dst  = out + ((mt < 2) ? HE_OFF : HI_OFF);
    #pragma unroll
    for (int nt = 0; nt < 4; ++nt) {
      int pix = wid*64 + nt*16 + xl;
      int gy = ty0 + (pix >> 4), gx = tx0 + (pix & 15);
      #pragma unroll
      for (int r = 0; r < 4; ++r) {
        int ch = (mt*16 + q*4 + r) & 31;
        size_t idx = (((size_t)b*C + ch)*H + gy)*W + gx;
        float it = tv[r];
        dst[idx] = (1.f - it)*hsrc[idx] + it*fast_tanh(acc[mt][nt][r]);
      }
    }
  }
}

__global__ __launch_bounds__(256) void out_kernel_fb(
    const unsigned char* __restrict__ ws, float* __restrict__ out) {
  __shared__ f32x4 smem[2448];
  _Float16* tile = (_Float16*)smem;
  f32x4*    wlds = smem + 1296;

  const int b   = blockIdx.z;
  const int ty0 = blockIdx.y * 16, tx0 = blockIdx.x * 16;
  const int tid = threadIdx.x;
  const int wid = tid >> 6, l = tid & 63;
  const int q   = l >> 4, xl = l & 15;

  const float* bout = (const float*)(ws + WSB_BOUT);
  const float* src  = out + HE_OFF + (size_t)b*C*H*W;

  f32x4 acc[2][4];
  #pragma unroll
  for (int mt = 0; mt < 2; ++mt) {
    f32x4 bv = *(const f32x4*)(bout + mt*16 + q*4);
    #pragma unroll
    for (int nt = 0; nt < 4; ++nt) acc[mt][nt] = bv;
  }

  for (int i = tid; i < 10368; i += 256) {
    int c = i / 324, rem = i % 324;
    int yy = rem / 18, xx = rem % 18;
    int gr = ty0 - 1 + yy, gc = tx0 - 1 + xx;
    float v = ((unsigned)gr < H && (unsigned)gc < W) ? src[(c*H + gr)*W + gc] : 0.f;
    int baddr = yy*1152 + xx*64 + (((c>>3) ^ ((xx>>1)&3)) << 4) + ((c&7) << 1);
    tile[baddr >> 1] = (_Float16)v;
  }
  const f32x4* wsrc = (const f32x4*)(ws + WSB_WO);
  #pragma unroll
  for (int k2 = 0; k2 < 5; ++k2) {
    int off = k2*256 + tid;
    if (off < 1152) wlds[off] = wsrc[off];
  }
  __syncthreads();

  #pragma unroll
  for (int dy = 0; dy < 3; ++dy) {
    #pragma unroll
    for (int dx = 0; dx < 3; ++dx) {
      const int tap  = dy*3 + dx;
      const int xcol = xl + dx;
      const int swz  = (q ^ ((xcol>>1)&3)) << 4;
      half8 bf[4];
      #pragma unroll
      for (int nt = 0; nt < 4; ++nt) {
        int yrow = wid*4 + nt + dy;
        bf[nt] = *(const half8*)((const char*)tile + yrow*1152 + xcol*64 + swz);
      }
      #pragma unroll
      for (int mt = 0; mt < 2; ++mt) {
        half8 af = *(const half8*)((const char*)wlds + ((tap*2 + mt)*64 + l)*16);
        #pragma unroll
        for (int nt = 0; nt < 4; ++nt)
          acc[mt][nt] = __builtin_amdgcn_mfma_f32_16x16x32_f16(af, bf[nt], acc[mt][nt], 0, 0, 0);
      }
    }
  }

  #pragma unroll
  for (int mt = 0; mt < 2; ++mt) {
    #pragma unroll
    for (int nt = 0; nt < 4; ++nt) {
      int pix = wid*64 + nt*16 + xl;
      int gy = ty0 + (pix >> 4), gx = tx0 + (pix & 15);
      #pragma unroll
      for (int r = 0; r < 4; ++r) {
        int ch = mt*16 + q*4 + r;
        out[(((size_t)b*C + ch)*H + gy)*W + gx] = fast_tanh(acc[mt][nt][r]);
      }
    }
  }
}

// ---------------- launch --------------------------------------------------
extern "C" void kernel_launch(void* const* d_in, const int* in_sizes, int n_in,
                              void* d_out, int out_size, void* d_ws, size_t ws_size,
                              hipStream_t stream) {
  const float* x      = (const float*)d_in[0];
  const float* h_e    = (const float*)d_in[1];
  const float* h_i    = (const float*)d_in[2];
  const float* W_in_e = (const float*)d_in[3];
  const float* b_in_e = (const float*)d_in[4];
  const float* W_in_i = (const float*)d_in[5];
  const float* b_in_i = (const float*)d_in[6];
  const float* W_e_e  = (const float*)d_in[7];
  const float* b_e_e  = (const float*)d_in[8];
  const float* W_e_i  = (const float*)d_in[9];
  const float* b_e_i  = (const float*)d_in[10];
  const float* W_e_out= (const float*)d_in[11];
  const float* b_e_out= (const float*)d_in[12];
  const float* W_i_e  = (const float*)d_in[13];
  const float* b_i_e  = (const float*)d_in[14];
  const float* W_i_i  = (const float*)d_in[15];
  const float* b_i_i  = (const float*)d_in[16];
  const float* tau_e  = (const float*)d_in[17];
  const float* tau_i  = (const float*)d_in[18];

  unsigned char* ws = (unsigned char*)d_ws;
  float* out = (float*)d_out;

  prep_kernel<<<216, 256, 0, stream>>>(W_in_e, b_in_e, W_in_i, b_in_i,
                                       W_e_e, b_e_e, W_e_i, b_e_i,
                                       W_e_out, b_e_out, W_i_e, b_i_e,
                                       W_i_i, b_i_i, tau_e, tau_i, ws);

  dim3 grid(W/16, H/16, BB);   // 8 x 8 x 16 = 1024 blocks

  if (ws_size >= WS_NEED) {
    convert_kernel<<<BB*H, 128, 0, stream>>>(x, h_e, h_i, ws);
    cell_kernel<<<grid, 256, 0, stream>>>(ws, out);
    out_kernel<<<grid, 256, 0, stream>>>(ws, out);
  } else {
    cell_kernel_fb<<<grid, 256, 0, stream>>>(x, h_e, h_i, ws, out);
    out_kernel_fb<<<grid, 256, 0, stream>>>(ws, out);
  }
}